// Round 1
// baseline (164.236 us; speedup 1.0000x reference)
//
#include <hip/hip_runtime.h>
#include <hip/hip_bf16.h>
#include <cfloat>

#define BB 16
#define NN 512
#define DIMX 78
#define NH 6
#define DHH 13
#define NC (NH*3*DHH)              // 234
#define SCALE 0.27735009811261457f // 13^-0.5
#define LAM_A 1.0f
#define LAM_G 0.5f

// ---------------- QKV projection: (B*N, 78) @ (78, 234) ----------------
__global__ __launch_bounds__(256) void qkv_kernel(
    const float* __restrict__ x, const float* __restrict__ Wqkv,
    float* __restrict__ q, float* __restrict__ k, float* __restrict__ v) {
  const int total = BB * NN * NC;
  for (int idx = blockIdx.x * blockDim.x + threadIdx.x; idx < total;
       idx += gridDim.x * blockDim.x) {
    int col = idx % NC;
    int bn  = idx / NC;
    const float* xr = x + (size_t)bn * DIMX;
    float acc = 0.f;
#pragma unroll
    for (int d = 0; d < DIMX; ++d) acc = fmaf(xr[d], Wqkv[d * NC + col], acc);
    int h  = col / (3 * DHH);
    int rm = col % (3 * DHH);
    int t  = rm / DHH;
    int dd = rm % DHH;
    int b = bn / NN, n = bn % NN;
    float* dst = (t == 0) ? q : ((t == 1) ? k : v);
    dst[(((size_t)b * NH + h) * NN + n) * DHH + dd] = acc;
  }
}

// ---------------- Fused masked softmax attention ----------------
// grid = B*H*(N/64); block = 256 (4 waves, each wave owns one row at a time)
__global__ __launch_bounds__(256) void attn_kernel(
    const float* __restrict__ q, const float* __restrict__ k,
    const float* __restrict__ v, const int* __restrict__ mask,
    const float* __restrict__ adj, float* __restrict__ att) {
  __shared__ float ks[NN][DHH];
  __shared__ float vs[NN][DHH];
  __shared__ unsigned char ms[NN];

  int blk   = blockIdx.x;
  int itile = blk & 7;       // N/64 = 8 tiles
  int bh    = blk >> 3;
  int b     = bh / NH;
  int h     = bh % NH;

  const float* kb = k + (size_t)bh * NN * DHH;
  const float* vb = v + (size_t)bh * NN * DHH;
  for (int idx = threadIdx.x; idx < NN * DHH; idx += 256) {
    ks[idx / DHH][idx % DHH] = kb[idx];
    vs[idx / DHH][idx % DHH] = vb[idx];
  }
  for (int j = threadIdx.x; j < NN; j += 256)
    ms[j] = (unsigned char)(mask[b * NN + j] != 0);
  __syncthreads();

  int wave = threadIdx.x >> 6;
  int lane = threadIdx.x & 63;

  for (int rr = 0; rr < 16; ++rr) {
    int i = itile * 64 + wave * 16 + rr;
    const float* qi = q + ((size_t)bh * NN + i) * DHH;
    float qreg[DHH];
#pragma unroll
    for (int d = 0; d < DHH; ++d) qreg[d] = qi[d];
    bool mi = ms[i] != 0;

    float s[8];
    float mx = -FLT_MAX;
#pragma unroll
    for (int jj = 0; jj < 8; ++jj) {
      int j = jj * 64 + lane;
      float dot = 0.f;
#pragma unroll
      for (int d = 0; d < DHH; ++d) dot = fmaf(qreg[d], ks[j][d], dot);
      float sv = (mi && ms[j]) ? dot * SCALE : -FLT_MAX;
      s[jj] = sv;
      mx = fmaxf(mx, sv);
    }
#pragma unroll
    for (int off = 32; off > 0; off >>= 1) mx = fmaxf(mx, __shfl_xor(mx, off));

    float sum = 0.f;
#pragma unroll
    for (int jj = 0; jj < 8; ++jj) {
      float p = __expf(s[jj] - mx);  // fully-masked row: exp(0)=1 -> uniform
      s[jj] = p;
      sum += p;
    }
#pragma unroll
    for (int off = 32; off > 0; off >>= 1) sum += __shfl_xor(sum, off);
    float inv = LAM_A / sum;

    const float* adjr = adj + ((size_t)b * NN + i) * NN;
    float acc[DHH];
#pragma unroll
    for (int d = 0; d < DHH; ++d) acc[d] = 0.f;
#pragma unroll
    for (int jj = 0; jj < 8; ++jj) {
      int j = jj * 64 + lane;
      float a = s[jj] * inv;
      if (mi && ms[j]) a = fmaf(LAM_G, adjr[j], a);
#pragma unroll
      for (int d = 0; d < DHH; ++d) acc[d] = fmaf(a, vs[j][d], acc[d]);
    }
#pragma unroll
    for (int off = 32; off > 0; off >>= 1) {
#pragma unroll
      for (int d = 0; d < DHH; ++d) acc[d] += __shfl_xor(acc[d], off);
    }
    if (lane == 0) {
#pragma unroll
      for (int d = 0; d < DHH; ++d)
        att[((size_t)b * NN + i) * DIMX + h * DHH + d] = acc[d];
    }
  }
}

// ---------------- Output projection: (B*N, 78) @ (78, 78) + b ----------------
// grid = B*N/32; each block: 32 rows
__global__ __launch_bounds__(256) void proj_kernel(
    const float* __restrict__ att, const float* __restrict__ Wout,
    const float* __restrict__ bout, float* __restrict__ out) {
  __shared__ float Ws[DIMX * DIMX];
  __shared__ float bs[DIMX];
  __shared__ float as[32][DIMX];
  for (int idx = threadIdx.x; idx < DIMX * DIMX; idx += 256) Ws[idx] = Wout[idx];
  if (threadIdx.x < DIMX) bs[threadIdx.x] = bout[threadIdx.x];
  size_t row0 = (size_t)blockIdx.x * 32;
  for (int idx = threadIdx.x; idx < 32 * DIMX; idx += 256)
    as[idx / DIMX][idx % DIMX] = att[row0 * DIMX + idx];
  __syncthreads();
  for (int e = threadIdx.x; e < 32 * DIMX; e += 256) {
    int r = e / DIMX, c = e % DIMX;
    float acc = bs[c];
#pragma unroll
    for (int d = 0; d < DIMX; ++d) acc = fmaf(as[r][d], Ws[d * DIMX + c], acc);
    out[(row0 + r) * DIMX + c] = acc;
  }
}

extern "C" void kernel_launch(void* const* d_in, const int* in_sizes, int n_in,
                              void* d_out, int out_size, void* d_ws, size_t ws_size,
                              hipStream_t stream) {
  const float* x    = (const float*)d_in[0];
  const int*   mask = (const int*)d_in[1];
  const float* adj  = (const float*)d_in[2];
  const float* Wqkv = (const float*)d_in[3];
  const float* Wout = (const float*)d_in[4];
  const float* bout = (const float*)d_in[5];
  float* out = (float*)d_out;

  const size_t qkv_elems = (size_t)BB * NH * NN * DHH;  // 638,976
  float* q   = (float*)d_ws;
  float* k   = q + qkv_elems;
  float* v   = k + qkv_elems;
  float* att = v + qkv_elems;  // B*N*78

  qkv_kernel<<<2048, 256, 0, stream>>>(x, Wqkv, q, k, v);
  attn_kernel<<<BB * NH * (NN / 64), 256, 0, stream>>>(q, k, v, mask, adj, att);
  proj_kernel<<<BB * NN / 32, 256, 0, stream>>>(att, Wout, bout, out);
}

// Round 2
// 142.269 us; speedup vs baseline: 1.1544x; 1.1544x over previous
//
#include <hip/hip_runtime.h>
#include <hip/hip_bf16.h>
#include <cfloat>

#define BB 16
#define NN 512
#define DIMX 78
#define NH 6
#define DHH 13
#define NC (NH*3*DHH)              // 234
#define SCALE 0.27735009811261457f // 13^-0.5
#define LAM_A 1.0f
#define LAM_G 0.5f
#define NU 32                      // max 512/16 t-iterations per lane

// ---------------- QKV projection: (B*N, 78) @ (78, 234) ----------------
__global__ __launch_bounds__(256) void qkv_kernel(
    const float* __restrict__ x, const float* __restrict__ Wqkv,
    float* __restrict__ q, float* __restrict__ k, float* __restrict__ v) {
  const int total = BB * NN * NC;
  for (int idx = blockIdx.x * blockDim.x + threadIdx.x; idx < total;
       idx += gridDim.x * blockDim.x) {
    int col = idx % NC;
    int bn  = idx / NC;
    const float* xr = x + (size_t)bn * DIMX;
    float acc = 0.f;
#pragma unroll
    for (int d = 0; d < DIMX; ++d) acc = fmaf(xr[d], Wqkv[d * NC + col], acc);
    int h  = col / (3 * DHH);
    int rm = col % (3 * DHH);
    int t  = rm / DHH;
    int dd = rm % DHH;
    int b = bn / NN, n = bn % NN;
    float* dst = (t == 0) ? q : ((t == 1) ? k : v);
    dst[(((size_t)b * NH + h) * NN + n) * DHH + dd] = acc;
  }
}

// ---------------- Fused masked softmax attention (compacted) ----------------
// grid = B*H*(N/64) = 768 blocks; block = 256 (4 waves).
// Active rows/cols compacted via deterministic prefix scans; fully-masked
// rows get the closed-form uniform output vsum/512.
__global__ __launch_bounds__(256) void attn_kernel(
    const float* __restrict__ q, const float* __restrict__ k,
    const float* __restrict__ v, const int* __restrict__ mask,
    const float* __restrict__ adj, float* __restrict__ att) {
  __shared__ float ksc[NN][DHH];      // compacted K
  __shared__ float vsc[NN][DHH];      // compacted V
  __shared__ short jact[NN];          // active col indices (ascending)
  __shared__ unsigned char ract[64];  // active row offsets within tile
  __shared__ float vsum[DHH];
  __shared__ int nact_s, nract_s;

  int blk   = blockIdx.x;
  int itile = blk & 7;
  int bh    = blk >> 3;
  int b     = bh / NH;
  int h     = bh % NH;
  int i0    = itile * 64;

  const float* kb = k + (size_t)bh * NN * DHH;
  const float* vb = v + (size_t)bh * NN * DHH;
  const int* mrow = mask + b * NN;

  int tid  = threadIdx.x;
  int wave = tid >> 6, lane = tid & 63;

  if (wave == 0) {
    // column compaction: lane owns 8 j's, ballot-free prefix scan over lanes
    unsigned m8 = 0;
#pragma unroll
    for (int t = 0; t < 8; ++t) {
      int j = lane * 8 + t;
      if (mrow[j] != 0) m8 |= (1u << t);
    }
    int cnt = __popc(m8);
    int pre = cnt;
#pragma unroll
    for (int off = 1; off < 64; off <<= 1) {
      int o = __shfl_up(pre, off);
      if (lane >= off) pre += o;
    }
    pre -= cnt;  // exclusive
    int w = pre;
#pragma unroll
    for (int t = 0; t < 8; ++t)
      if ((m8 >> t) & 1) jact[w++] = (short)(lane * 8 + t);
    if (lane == 63) nact_s = pre + cnt;
  } else if (wave == 1) {
    // row compaction for this 64-row tile
    int a = (mrow[i0 + lane] != 0) ? 1 : 0;
    int pre = a;
#pragma unroll
    for (int off = 1; off < 64; off <<= 1) {
      int o = __shfl_up(pre, off);
      if (lane >= off) pre += o;
    }
    pre -= a;
    if (a) ract[pre] = (unsigned char)lane;
    if (lane == 63) nract_s = pre + a;
  } else if (wave == 2) {
    // vsum[d] = sum over ALL 512 v rows (uniform-softmax fast path), 4 parts
    int d = lane % DHH;
    int part = lane / DHH;  // 0..4 (part 4 idle)
    float sacc = 0.f;
    if (part < 4) {
      for (int n = part * 128; n < (part + 1) * 128; ++n)
        sacc += vb[n * DHH + d];
    }
    float t1 = __shfl(sacc, d + DHH);
    float t2 = __shfl(sacc, d + 2 * DHH);
    float t3 = __shfl(sacc, d + 3 * DHH);
    if (lane < DHH) vsum[lane] = sacc + t1 + t2 + t3;
  }
  __syncthreads();

  int na = nact_s;
  int nr = nract_s;

  // stage compacted K,V
  for (int t = tid; t < na; t += 256) {
    int j = jact[t];
#pragma unroll
    for (int d = 0; d < DHH; ++d) {
      ksc[t][d] = kb[j * DHH + d];
      vsc[t][d] = vb[j * DHH + d];
    }
  }
  // fully-masked rows: uniform softmax over all 512, zero adjacency
  for (int e = tid; e < 64 * DHH; e += 256) {
    int r = e / DHH, d = e % DHH;
    int i = i0 + r;
    if (mrow[i] == 0)
      att[((size_t)b * NN + i) * DIMX + h * DHH + d] = (LAM_A / 512.f) * vsum[d];
  }
  __syncthreads();

  // main loop: 16 lanes per row, 4 rows per wave in flight
  int grp = lane >> 4;
  int li  = lane & 15;

  for (int base = wave * 4; base < nr; base += 16) {
    int ridx = base + grp;
    bool rok = ridx < nr;
    int i = i0 + ract[rok ? ridx : 0];
    const float* qi = q + ((size_t)bh * NN + i) * DHH;
    float qreg[DHH];
#pragma unroll
    for (int d = 0; d < DHH; ++d) qreg[d] = qi[d] * SCALE;

    float s[NU];
    float mx = -FLT_MAX;
#pragma unroll
    for (int u = 0; u < NU; ++u) {
      int t = u * 16 + li;
      if (t < na) {
        float dot = 0.f;
#pragma unroll
        for (int d = 0; d < DHH; ++d) dot = fmaf(qreg[d], ksc[t][d], dot);
        s[u] = dot;
        mx = fmaxf(mx, dot);
      } else {
        s[u] = 0.f;
      }
    }
#pragma unroll
    for (int off = 1; off < 16; off <<= 1) mx = fmaxf(mx, __shfl_xor(mx, off));

    float sum = 0.f;
#pragma unroll
    for (int u = 0; u < NU; ++u) {
      int t = u * 16 + li;
      if (t < na) {
        float p = __expf(s[u] - mx);
        s[u] = p;
        sum += p;
      }
    }
#pragma unroll
    for (int off = 1; off < 16; off <<= 1) sum += __shfl_xor(sum, off);
    float inv = LAM_A / sum;

    // fold normalized softmax + adjacency into s (issues all adj gathers early)
    const float* adjr = adj + ((size_t)b * NN + i) * NN;
#pragma unroll
    for (int u = 0; u < NU; ++u) {
      int t = u * 16 + li;
      if (t < na) s[u] = fmaf(LAM_G, adjr[jact[t]], s[u] * inv);
    }

    float acc[DHH];
#pragma unroll
    for (int d = 0; d < DHH; ++d) acc[d] = 0.f;
#pragma unroll
    for (int u = 0; u < NU; ++u) {
      int t = u * 16 + li;
      if (t < na) {
        float a = s[u];
#pragma unroll
        for (int d = 0; d < DHH; ++d) acc[d] = fmaf(a, vsc[t][d], acc[d]);
      }
    }
#pragma unroll
    for (int off = 1; off < 16; off <<= 1) {
#pragma unroll
      for (int d = 0; d < DHH; ++d) acc[d] += __shfl_xor(acc[d], off);
    }

    if (rok && li == 0) {
#pragma unroll
      for (int d = 0; d < DHH; ++d)
        att[((size_t)b * NN + i) * DIMX + h * DHH + d] = acc[d];
    }
  }
}

// ---------------- Output projection: (B*N, 78) @ (78, 78) + b ----------------
__global__ __launch_bounds__(256) void proj_kernel(
    const float* __restrict__ att, const float* __restrict__ Wout,
    const float* __restrict__ bout, float* __restrict__ out) {
  __shared__ float Ws[DIMX * DIMX];
  __shared__ float bs[DIMX];
  __shared__ float as[32][DIMX];
  for (int idx = threadIdx.x; idx < DIMX * DIMX; idx += 256) Ws[idx] = Wout[idx];
  if (threadIdx.x < DIMX) bs[threadIdx.x] = bout[threadIdx.x];
  size_t row0 = (size_t)blockIdx.x * 32;
  for (int idx = threadIdx.x; idx < 32 * DIMX; idx += 256)
    as[idx / DIMX][idx % DIMX] = att[row0 * DIMX + idx];
  __syncthreads();
  for (int e = threadIdx.x; e < 32 * DIMX; e += 256) {
    int r = e / DIMX, c = e % DIMX;
    float acc = bs[c];
#pragma unroll
    for (int d = 0; d < DIMX; ++d) acc = fmaf(as[r][d], Ws[d * DIMX + c], acc);
    out[(row0 + r) * DIMX + c] = acc;
  }
}

extern "C" void kernel_launch(void* const* d_in, const int* in_sizes, int n_in,
                              void* d_out, int out_size, void* d_ws, size_t ws_size,
                              hipStream_t stream) {
  const float* x    = (const float*)d_in[0];
  const int*   mask = (const int*)d_in[1];
  const float* adj  = (const float*)d_in[2];
  const float* Wqkv = (const float*)d_in[3];
  const float* Wout = (const float*)d_in[4];
  const float* bout = (const float*)d_in[5];
  float* out = (float*)d_out;

  const size_t qkv_elems = (size_t)BB * NH * NN * DHH;  // 638,976
  float* q   = (float*)d_ws;
  float* k   = q + qkv_elems;
  float* v   = k + qkv_elems;
  float* att = v + qkv_elems;  // B*N*78

  qkv_kernel<<<2048, 256, 0, stream>>>(x, Wqkv, q, k, v);
  attn_kernel<<<BB * NH * (NN / 64), 256, 0, stream>>>(q, k, v, mask, adj, att);
  proj_kernel<<<BB * NN / 32, 256, 0, stream>>>(att, Wout, bout, out);
}

// Round 3
// 77.083 us; speedup vs baseline: 2.1306x; 1.8457x over previous
//
#include <hip/hip_runtime.h>
#include <hip/hip_bf16.h>
#include <cfloat>

#define BB 16
#define NN 512
#define DIMX 78
#define NH 6
#define DHH 13
#define NC (NH*3*DHH)              // 234
#define SCALE 0.27735009811261457f // 13^-0.5
#define LAM_A 1.0f
#define LAM_G 0.5f
#define NU 32                      // max 512/16 t-iterations per lane

typedef unsigned short ushortx;
typedef ushortx ushort8 __attribute__((ext_vector_type(8)));

__device__ __forceinline__ ushortx f2bf(float f) {
  unsigned u = __float_as_uint(f);
  unsigned r = (u + 0x7FFFu + ((u >> 16) & 1u)) >> 16;
  return (ushortx)r;
}
__device__ __forceinline__ float bf2f(ushortx h) {
  return __uint_as_float(((unsigned)h) << 16);
}

// ---------------- QKV projection: (B*N, 78) @ (78, 234) ----------------
// thread = 4 rows x 4 cols register tile
__global__ __launch_bounds__(256) void qkv_kernel(
    const float* __restrict__ x, const float* __restrict__ Wqkv,
    float* __restrict__ q, float* __restrict__ k, float* __restrict__ v) {
  int idx = blockIdx.x * 256 + threadIdx.x;
  const int NQ = 59;  // col quads (236/4), clamped
  int rq = idx / NQ, cq = idx % NQ;
  if (rq >= (BB * NN) / 4) return;
  int c0 = cq * 4; if (c0 > NC - 4) c0 = NC - 4;
  int r0 = rq * 4;
  const float* x0 = x + (size_t)r0 * DIMX;

  float acc[4][4];
#pragma unroll
  for (int r = 0; r < 4; ++r)
#pragma unroll
    for (int c = 0; c < 4; ++c) acc[r][c] = 0.f;

#pragma unroll 6
  for (int d = 0; d < DIMX; ++d) {
    float w0 = Wqkv[d * NC + c0 + 0];
    float w1 = Wqkv[d * NC + c0 + 1];
    float w2 = Wqkv[d * NC + c0 + 2];
    float w3 = Wqkv[d * NC + c0 + 3];
#pragma unroll
    for (int r = 0; r < 4; ++r) {
      float xv = x0[r * DIMX + d];
      acc[r][0] = fmaf(xv, w0, acc[r][0]);
      acc[r][1] = fmaf(xv, w1, acc[r][1]);
      acc[r][2] = fmaf(xv, w2, acc[r][2]);
      acc[r][3] = fmaf(xv, w3, acc[r][3]);
    }
  }
#pragma unroll
  for (int r = 0; r < 4; ++r) {
    int bn = r0 + r;
    int b = bn / NN, n = bn % NN;
#pragma unroll
    for (int c = 0; c < 4; ++c) {
      int col = c0 + c;
      int h  = col / (3 * DHH);
      int rm = col % (3 * DHH);
      int t  = rm / DHH;
      int dd = rm % DHH;
      float* dst = (t == 0) ? q : ((t == 1) ? k : v);
      dst[(((size_t)b * NH + h) * NN + n) * DHH + dd] = acc[r][c];
    }
  }
}

// ---------------- Fused masked softmax attention (compacted, bf16 LDS) ----
// grid = B*H*(N/64) = 768 blocks; block = 256 (4 waves), 4 blocks/CU.
__global__ __launch_bounds__(256, 4) void attn_kernel(
    const float* __restrict__ q, const float* __restrict__ k,
    const float* __restrict__ v, const int* __restrict__ mask,
    const float* __restrict__ adj, float* __restrict__ att) {
  __shared__ ushort8 k0s[NN], k1s[NN];  // K rows: d0..7, d8..12+pad
  __shared__ ushort8 v0s[NN], v1s[NN];
  __shared__ short jact[NN];
  __shared__ unsigned char ract[64];
  __shared__ float vsum[DHH];
  __shared__ int nact_s, nract_s;

  int blk   = blockIdx.x;
  int itile = blk & 7;
  int bh    = blk >> 3;
  int b     = bh / NH;
  int h     = bh % NH;
  int i0    = itile * 64;

  const float* kb = k + (size_t)bh * NN * DHH;
  const float* vb = v + (size_t)bh * NN * DHH;
  const int* mrow = mask + b * NN;

  int tid  = threadIdx.x;
  int wave = tid >> 6, lane = tid & 63;

  if (wave == 0) {
    unsigned m8 = 0;
#pragma unroll
    for (int t = 0; t < 8; ++t) {
      int j = lane * 8 + t;
      if (mrow[j] != 0) m8 |= (1u << t);
    }
    int cnt = __popc(m8);
    int pre = cnt;
#pragma unroll
    for (int off = 1; off < 64; off <<= 1) {
      int o = __shfl_up(pre, off);
      if (lane >= off) pre += o;
    }
    pre -= cnt;
    int w = pre;
#pragma unroll
    for (int t = 0; t < 8; ++t)
      if ((m8 >> t) & 1) jact[w++] = (short)(lane * 8 + t);
    if (lane == 63) nact_s = pre + cnt;
  } else if (wave == 1) {
    int a = (mrow[i0 + lane] != 0) ? 1 : 0;
    int pre = a;
#pragma unroll
    for (int off = 1; off < 64; off <<= 1) {
      int o = __shfl_up(pre, off);
      if (lane >= off) pre += o;
    }
    pre -= a;
    if (a) ract[pre] = (unsigned char)lane;
    if (lane == 63) nract_s = pre + a;
  } else if (wave == 2) {
    int d = lane % DHH;
    int part = lane / DHH;
    float sacc = 0.f;
    if (part < 4) {
      for (int n = part * 128; n < (part + 1) * 128; ++n)
        sacc += vb[n * DHH + d];
    }
    float t1 = __shfl(sacc, d + DHH);
    float t2 = __shfl(sacc, d + 2 * DHH);
    float t3 = __shfl(sacc, d + 3 * DHH);
    if (lane < DHH) vsum[lane] = sacc + t1 + t2 + t3;
  }
  __syncthreads();

  int na = nact_s;
  int nr = nract_s;

  // stage compacted K,V as bf16; zero tails (incl. jact) for safe reads
  for (int t = tid; t < NN; t += 256) {
    if (t < na) {
      int j = jact[t];
      const float* kr = kb + j * DHH;
      const float* vr = vb + j * DHH;
      ushort8 a0, a1, c0v, c1;
#pragma unroll
      for (int d = 0; d < 8; ++d) { a0[d] = f2bf(kr[d]); c0v[d] = f2bf(vr[d]); }
#pragma unroll
      for (int d = 0; d < 5; ++d) { a1[d] = f2bf(kr[8 + d]); c1[d] = f2bf(vr[8 + d]); }
#pragma unroll
      for (int d = 5; d < 8; ++d) { a1[d] = 0; c1[d] = 0; }
      k0s[t] = a0; k1s[t] = a1; v0s[t] = c0v; v1s[t] = c1;
    } else {
      ushort8 z = (ushort8)0;
      k0s[t] = z; k1s[t] = z; v0s[t] = z; v1s[t] = z;
      jact[t] = 0;
    }
  }
  // fully-masked rows: uniform softmax over all 512, zero adjacency
  for (int e = tid; e < 64 * DHH; e += 256) {
    int r = e / DHH, d = e % DHH;
    int i = i0 + r;
    if (mrow[i] == 0)
      att[((size_t)b * NN + i) * DIMX + h * DHH + d] = (LAM_A / 512.f) * vsum[d];
  }
  __syncthreads();

  int grp = lane >> 4;
  int li  = lane & 15;

  for (int base = wave * 4; base < nr; base += 16) {
    int ridx = base + grp;
    bool rok = ridx < nr;
    int i = i0 + ract[rok ? ridx : 0];
    const float* qi = q + ((size_t)bh * NN + i) * DHH;
    float qreg[DHH];
#pragma unroll
    for (int d = 0; d < DHH; ++d) qreg[d] = qi[d] * SCALE;
    const float* adjr = adj + ((size_t)b * NN + i) * NN;

    float s[NU], aj[NU];
    float mx = -FLT_MAX;
#pragma unroll
    for (int u = 0; u < NU; ++u) {
      if (u * 16 < na) {  // wave-uniform branch
        int t = u * 16 + li;
        ushort8 ka = k0s[t];
        ushort8 kc = k1s[t];
        aj[u] = adjr[jact[t]];  // prefetched here, consumed after softmax
        float dot = 0.f;
#pragma unroll
        for (int d = 0; d < 8; ++d) dot = fmaf(qreg[d], bf2f(ka[d]), dot);
#pragma unroll
        for (int d = 0; d < 5; ++d) dot = fmaf(qreg[8 + d], bf2f(kc[d]), dot);
        s[u] = (t < na) ? dot : -FLT_MAX;
        mx = fmaxf(mx, s[u]);
      }
    }
#pragma unroll
    for (int off = 1; off < 16; off <<= 1) mx = fmaxf(mx, __shfl_xor(mx, off));

    float sum = 0.f;
#pragma unroll
    for (int u = 0; u < NU; ++u) {
      if (u * 16 < na) {
        float p = __expf(s[u] - mx);
        s[u] = p;
        sum += p;
      }
    }
#pragma unroll
    for (int off = 1; off < 16; off <<= 1) sum += __shfl_xor(sum, off);
    float inv = LAM_A / sum;

    float acc[DHH];
#pragma unroll
    for (int d = 0; d < DHH; ++d) acc[d] = 0.f;
#pragma unroll
    for (int u = 0; u < NU; ++u) {
      if (u * 16 < na) {
        int t = u * 16 + li;
        ushort8 va = v0s[t];
        ushort8 vc = v1s[t];
        float wu = fmaf(LAM_G, aj[u], s[u] * inv);  // tail rows: v==0 -> 0
#pragma unroll
        for (int d = 0; d < 8; ++d) acc[d] = fmaf(wu, bf2f(va[d]), acc[d]);
#pragma unroll
        for (int d = 0; d < 5; ++d) acc[8 + d] = fmaf(wu, bf2f(vc[d]), acc[8 + d]);
      }
    }
#pragma unroll
    for (int off = 1; off < 16; off <<= 1) {
#pragma unroll
      for (int d = 0; d < DHH; ++d) acc[d] += __shfl_xor(acc[d], off);
    }

    if (rok && li == 0) {
#pragma unroll
      for (int d = 0; d < DHH; ++d)
        att[((size_t)b * NN + i) * DIMX + h * DHH + d] = acc[d];
    }
  }
}

// ---------------- Output projection: (B*N, 78) @ (78, 78) + b ----------------
__global__ __launch_bounds__(256) void proj_kernel(
    const float* __restrict__ att, const float* __restrict__ Wout,
    const float* __restrict__ bout, float* __restrict__ out) {
  __shared__ float Ws[DIMX * DIMX];
  __shared__ float bs[DIMX];
  __shared__ float as[32][DIMX];
  for (int idx = threadIdx.x; idx < DIMX * DIMX; idx += 256) Ws[idx] = Wout[idx];
  if (threadIdx.x < DIMX) bs[threadIdx.x] = bout[threadIdx.x];
  size_t row0 = (size_t)blockIdx.x * 32;
  for (int idx = threadIdx.x; idx < 32 * DIMX; idx += 256)
    as[idx / DIMX][idx % DIMX] = att[row0 * DIMX + idx];
  __syncthreads();
  for (int e = threadIdx.x; e < 32 * DIMX; e += 256) {
    int r = e / DIMX, c = e % DIMX;
    float acc = bs[c];
#pragma unroll
    for (int d = 0; d < DIMX; ++d) acc = fmaf(as[r][d], Ws[d * DIMX + c], acc);
    out[(row0 + r) * DIMX + c] = acc;
  }
}

extern "C" void kernel_launch(void* const* d_in, const int* in_sizes, int n_in,
                              void* d_out, int out_size, void* d_ws, size_t ws_size,
                              hipStream_t stream) {
  const float* x    = (const float*)d_in[0];
  const int*   mask = (const int*)d_in[1];
  const float* adj  = (const float*)d_in[2];
  const float* Wqkv = (const float*)d_in[3];
  const float* Wout = (const float*)d_in[4];
  const float* bout = (const float*)d_in[5];
  float* out = (float*)d_out;

  const size_t qkv_elems = (size_t)BB * NH * NN * DHH;
  float* q   = (float*)d_ws;
  float* k   = q + qkv_elems;
  float* v   = k + qkv_elems;
  float* att = v + qkv_elems;

  const int NQ = 59;
  int qkv_threads = (BB * NN / 4) * NQ;  // 120832
  qkv_kernel<<<(qkv_threads + 255) / 256, 256, 0, stream>>>(x, Wqkv, q, k, v);
  attn_kernel<<<BB * NH * (NN / 64), 256, 0, stream>>>(q, k, v, mask, adj, att);
  proj_kernel<<<BB * NN / 32, 256, 0, stream>>>(att, Wout, bout, out);
}